// Round 4
// baseline (230.529 us; speedup 1.0000x reference)
//
#include <hip/hip_runtime.h>
#include <hip/hip_cooperative_groups.h>

namespace cg = cooperative_groups;

#define N 4096
#define F 64
#define BZ 4
#define NCH 1024         // chunks per batch
#define RPC 4            // sorted rows per chunk
#define NC 65            // 64 features + 1 denominator component

// Single cooperative kernel: grid 256 x 1024 (1 block/CU, 16 waves).
// P0 kq -> P1 rank -> P2 chunk totals -> P3 scans -> P4 epilogue,
// separated by grid.sync() (replaces 4 kernel-launch boundaries).
__global__ __launch_bounds__(1024) void fused_kernel(
        const float* __restrict__ x, const float* __restrict__ wk,
        const float* __restrict__ wq, float* __restrict__ kq,
        float* __restrict__ q_sorted, int* __restrict__ id_sorted,
        int* __restrict__ p_arr, float* __restrict__ tot1,
        float* __restrict__ tot2, float* __restrict__ out) {
    cg::grid_group grid = cg::this_grid();
    __shared__ __align__(16) float qs[N];          // 16 KB (P1)
    __shared__ unsigned short pc[16][64];          // 2 KB
    __shared__ unsigned short pc2[16][64];         // 2 KB
    __shared__ float tile[64 * 65];                // 16.6 KB (P4)

    int tid = threadIdx.x;
    int wave = tid >> 6, lane = tid & 63;
    int bid = blockIdx.x;

    // ---- P0: k/q dot products. 4096 waves x 4 rows. ----
    {
        float wkv = wk[lane], wqv = wq[lane];
        int gw = bid * 16 + wave;
#pragma unroll
        for (int s = 0; s < 4; ++s) {
            int row = gw * 4 + s;                  // 0..BZ*N-1 (row = b*N+i)
            float xv = x[(size_t)row * F + lane];
            float kk = xv * wkv, qq = xv * wqv;
            for (int off = 32; off > 0; off >>= 1) {
                kk += __shfl_down(kk, off, 64);
                qq += __shfl_down(qq, off, 64);
            }
            if (lane == 0) {
                kq[row] = kk;                      // k block
                kq[BZ * N + row] = qq;             // q block
            }
        }
    }
    grid.sync();

    // ---- P1: counting rank-sort + split points. Block owns 64 j's. ----
    {
        int b = bid >> 6;
        const float* qb = kq + BZ * N + b * N;
        for (int t = tid; t < N; t += 1024) qs[t] = qb[t];
        __syncthreads();

        int j = (bid & 63) * 64 + lane;
        float qj = qs[j];
        float theta = -kq[b * N + j];
        int cnt = 0, cnt2 = 0;
        const float4* q4 = (const float4*)qs;
        int s0 = wave * 64;                        // float4 units
#pragma unroll 8
        for (int t4 = 0; t4 < 64; ++t4) {
            float4 v = q4[s0 + t4];
            int sb = (s0 + t4) * 4;
            cnt  += (int)((v.x < qj) | ((v.x == qj) & (sb + 0 < j)));
            cnt  += (int)((v.y < qj) | ((v.y == qj) & (sb + 1 < j)));
            cnt  += (int)((v.z < qj) | ((v.z == qj) & (sb + 2 < j)));
            cnt  += (int)((v.w < qj) | ((v.w == qj) & (sb + 3 < j)));
            cnt2 += (int)(v.x < theta) + (int)(v.y < theta)
                  + (int)(v.z < theta) + (int)(v.w < theta);
        }
        pc[wave][lane] = (unsigned short)cnt;
        pc2[wave][lane] = (unsigned short)cnt2;
        __syncthreads();

        if (wave == 0) {
            int r = 0, p = 0;
#pragma unroll
            for (int pp = 0; pp < 16; ++pp) { r += pc[pp][lane]; p += pc2[pp][lane]; }
            q_sorted[b * N + r] = qj;
            id_sorted[b * N + r] = j;
            p_arr[b * N + j] = p;
        }
    }
    grid.sync();

    // ---- P2: per-chunk totals. 4096 waves = 4096 chunks (RPC=4). ----
    {
        int c = bid * 16 + wave;                   // global chunk id
        int b = c >> 10, cl = c & (NCH - 1);
        const float* qsb = q_sorted + b * N;
        const int* idb = id_sorted + b * N;
        const float* xb = x + (size_t)b * N * F;
        float Qmax = qsb[N - 1];
        float a1 = 0.f, a2 = 0.f, s1 = 0.f, s2 = 0.f;
#pragma unroll
        for (int r = 0; r < RPC; ++r) {
            int t = cl * RPC + r;
            float d = qsb[t] - Qmax;
            int id = idb[t];
            float e1 = __expf(d);
            float e2 = __expf(0.2f * d);
            float xv = xb[(size_t)id * F + lane];
            a1 += e1 * xv; s1 += e1;
            a2 += e2 * xv; s2 += e2;
        }
        size_t row = (size_t)c * NC;
        tot1[row + lane] = a1;
        tot2[row + lane] = a2;
        if (lane == 0) { tot1[row + 64] = s1; tot2[row + 64] = s2; }
    }
    grid.sync();

    // ---- P3: exclusive scans over NCH chunks. 520 wave-jobs spread on CUs. ----
    {
        int job = wave * 256 + bid;                // waves 0,1 full; wave 2 partial
        if (job < 2 * BZ * NC) {
            int arr = job >= (BZ * NC);
            int rem = job - arr * (BZ * NC);
            int b = rem / NC, comp = rem % NC;
            float* base = (arr ? tot2 : tot1) + ((size_t)b * NCH) * NC + comp;
            float v[16];
#pragma unroll
            for (int t = 0; t < 16; ++t) {
                int e = lane * 16 + t;
                int c = arr ? e : (NCH - 1 - e);   // suffix = reversed prefix
                v[t] = base[(size_t)c * NC];
            }
            float s = 0.f;
#pragma unroll
            for (int t = 0; t < 16; ++t) s += v[t];
            float inc = s;
#pragma unroll
            for (int off = 1; off < 64; off <<= 1) {
                float o = __shfl_up(inc, off, 64);
                if (lane >= off) inc += o;
            }
            float run = inc - s;                   // exclusive across lanes
#pragma unroll
            for (int t = 0; t < 16; ++t) {
                int e = lane * 16 + t;
                int c = arr ? e : (NCH - 1 - e);
                float vv = v[t];
                base[(size_t)c * NC] = run;
                run += vv;
            }
        }
    }
    grid.sync();

    // ---- P4: epilogue. Block = 64-row tile; 16 waves x 4 rows. ----
    {
        int b = bid >> 6;
        int i0 = (bid & 63) * 64;
        const float* qsb = q_sorted + b * N;
        const int* idb = id_sorted + b * N;
        const float* xb = x + (size_t)b * N * F;
        float Qmax = qsb[N - 1];
#pragma unroll
        for (int s = 0; s < 4; ++s) {
            int il = wave * 4 + s;
            int i = i0 + il;
            float kk = kq[b * N + i];
            int p = p_arr[b * N + i];
            int c = p >> 2; if (c > NCH - 1) c = NCH - 1;
            int r0 = p - (c << 2);
            float u = kk + Qmax;
            float M = fmaxf(u, 0.2f * u);
            float c1 = __expf(u - M);
            float c2 = __expf(0.2f * u - M);
            size_t row = ((size_t)(b * NCH + c)) * NC;
            float a1 = tot1[row + lane], s1 = tot1[row + 64];
            float a2 = tot2[row + lane], s2 = tot2[row + 64];
            int tb = c << 2;
#pragma unroll
            for (int r = 0; r < RPC; ++r) {
                float d = qsb[tb + r] - Qmax;
                int id = idb[tb + r];
                float xv = xb[(size_t)id * F + lane];
                if (r >= r0) { float e1 = __expf(d);        a1 += e1 * xv; s1 += e1; }
                else         { float e2 = __expf(0.2f * d); a2 += e2 * xv; s2 += e2; }
            }
            float num = c1 * a1 + c2 * a2;
            float den = c1 * s1 + c2 * s2;
            tile[lane * 65 + il] = num / den;
        }
        __syncthreads();
#pragma unroll
        for (int rep = 0; rep < 4; ++rep) {
            int ff = rep * 16 + wave;
            out[((size_t)(b * F + ff)) * N + i0 + lane] = tile[ff * 65 + lane];
        }
    }
}

// ---------------------------------------------------------------------------
extern "C" void kernel_launch(void* const* d_in, const int* in_sizes, int n_in,
                              void* d_out, int out_size, void* d_ws, size_t ws_size,
                              hipStream_t stream) {
    const float* x  = (const float*)d_in[0];
    const float* wk = (const float*)d_in[1];
    const float* wq = (const float*)d_in[2];
    float* out = (float*)d_out;

    // ws layout (floats): kq[2*BZ*N] | q_sorted[BZ*N] | id_sorted[BZ*N] |
    //                     p_arr[BZ*N] | tot1[BZ*NCH*NC] | tot2[BZ*NCH*NC]
    float* ws = (float*)d_ws;
    float* kq        = ws;
    float* q_sorted  = ws + 2 * BZ * N;
    int*   id_sorted = (int*)(ws + 3 * BZ * N);
    int*   p_arr     = (int*)(ws + 4 * BZ * N);
    float* tot1      = ws + 5 * BZ * N;
    float* tot2      = tot1 + BZ * NCH * NC;

    void* args[] = {(void*)&x, (void*)&wk, (void*)&wq, (void*)&kq,
                    (void*)&q_sorted, (void*)&id_sorted, (void*)&p_arr,
                    (void*)&tot1, (void*)&tot2, (void*)&out};
    hipLaunchCooperativeKernel(reinterpret_cast<void*>(fused_kernel),
                               dim3(256), dim3(1024), args, 0, stream);
}

// Round 5
// 101.621 us; speedup vs baseline: 2.2685x; 2.2685x over previous
//
#include <hip/hip_runtime.h>

#define N 4096
#define F 64
#define BZ 4
#define NCH 1024         // chunks per batch
#define RPC 4            // sorted rows per chunk
#define NC 65            // 64 features + 1 denominator component

// order-preserving float <-> uint32 mapping
__device__ __forceinline__ unsigned int f2ord(float f) {
    unsigned int u = __float_as_uint(f);
    return (u & 0x80000000u) ? ~u : (u ^ 0x80000000u);
}
__device__ __forceinline__ float ord2f(unsigned int v) {
    unsigned int b = (v & 0x80000000u) ? (v ^ 0x80000000u) : ~v;
    return __uint_as_float(b);
}

// ---------------------------------------------------------------------------
// K1: k[b][i] = x·wk (float); qkey[b][i] = (ord(x·wq)<<32)|i. Wave per row.
// ---------------------------------------------------------------------------
__global__ __launch_bounds__(256) void kq_kernel(
        const float* __restrict__ x, const float* __restrict__ wk,
        const float* __restrict__ wq, float* __restrict__ karr,
        unsigned long long* __restrict__ qkey) {
    int wave = blockIdx.x * 4 + (threadIdx.x >> 6);
    int lane = threadIdx.x & 63;
    int row = wave;                     // 0..BZ*N-1
    float xv = x[(size_t)row * F + lane];
    float kk = xv * wk[lane];
    float qq = xv * wq[lane];
    for (int off = 32; off > 0; off >>= 1) {
        kk += __shfl_down(kk, off, 64);
        qq += __shfl_down(qq, off, 64);
    }
    if (lane == 0) {
        karr[row] = kk;
        qkey[row] = ((unsigned long long)f2ord(qq) << 32)
                  | (unsigned int)(row & (N - 1));
    }
}

// ---------------------------------------------------------------------------
// K2: counting rank-sort on u64 keys + split points + x permutation.
// grid BZ*64 x 1024. Block owns 64 j's; wave w counts over strip of 256 keys.
//   rank_j = #{s : key_s < key_j}           (strict total order, exact)
//   p_j    = #{s : ord(q_s) < ord(-k_j)}    (tie direction irrelevant: e^0)
// Then scatter xs[rank] = x[j] (coalesced 256B rows) and q_sorted[rank].
// ---------------------------------------------------------------------------
__global__ __launch_bounds__(1024) void rank_kernel(
        const float* __restrict__ x, const float* __restrict__ karr,
        const unsigned long long* __restrict__ qkey,
        float* __restrict__ q_sorted, int* __restrict__ p_arr,
        float* __restrict__ xs) {
    __shared__ __align__(16) unsigned long long qs[N];   // 32 KB
    __shared__ unsigned short pc[16][64];
    __shared__ unsigned short pc2[16][64];
    __shared__ unsigned short rs[64];
    int b = blockIdx.x >> 6;
    int tid = threadIdx.x;
    int wave = tid >> 6, lane = tid & 63;
    const unsigned long long* qb = qkey + b * N;
    for (int t = tid; t < N; t += 1024) qs[t] = qb[t];
    __syncthreads();

    int jbase = (blockIdx.x & 63) * 64;
    int j = jbase + lane;
    unsigned long long myKey = qs[j];
    unsigned int thOu = f2ord(-karr[b * N + j]);
    int cnt = 0, cnt2 = 0;
    const ulonglong2* q2 = (const ulonglong2*)qs;
    int s0 = wave * 128;                      // ulonglong2 units
#pragma unroll 8
    for (int t2 = 0; t2 < 128; ++t2) {
        ulonglong2 v = q2[s0 + t2];
        cnt  += (int)(v.x < myKey) + (int)(v.y < myKey);
        cnt2 += (int)((unsigned int)(v.x >> 32) < thOu)
              + (int)((unsigned int)(v.y >> 32) < thOu);
    }
    pc[wave][lane] = (unsigned short)cnt;
    pc2[wave][lane] = (unsigned short)cnt2;
    __syncthreads();

    if (wave == 0) {
        int r = 0, p = 0;
#pragma unroll
        for (int pp = 0; pp < 16; ++pp) { r += pc[pp][lane]; p += pc2[pp][lane]; }
        q_sorted[b * N + r] = ord2f((unsigned int)(myKey >> 32));
        p_arr[b * N + j] = p;
        rs[lane] = (unsigned short)r;
    }
    __syncthreads();

    // permute x into sorted order: 4 rows per wave, coalesced 256B each
#pragma unroll
    for (int s = 0; s < 4; ++s) {
        int jl = wave * 4 + s;
        int r = rs[jl];
        xs[((size_t)(b * N + r)) * F + lane] =
            x[((size_t)(b * N + jbase + jl)) * F + lane];
    }
}

// ---------------------------------------------------------------------------
// K3: per-chunk totals, RPC=4. grid BZ*NCH/4 x 256 (wave per chunk).
// Pure streaming now: xs rows are contiguous in sorted order.
// ---------------------------------------------------------------------------
__global__ __launch_bounds__(256) void chunk_kernel(
        const float* __restrict__ xs, const float* __restrict__ q_sorted,
        float* __restrict__ tot1, float* __restrict__ tot2) {
    int wave = threadIdx.x >> 6, lane = threadIdx.x & 63;
    int c = blockIdx.x * 4 + wave;            // global chunk 0..BZ*NCH-1
    int b = c >> 10;
    int cl = c & (NCH - 1);
    const float* qsb = q_sorted + b * N;
    float Qmax = qsb[N - 1];
    float a1 = 0.f, a2 = 0.f, s1 = 0.f, s2 = 0.f;
#pragma unroll
    for (int r = 0; r < RPC; ++r) {
        int t = cl * RPC + r;
        float d = qsb[t] - Qmax;
        float e1 = __expf(d);
        float e2 = __expf(0.2f * d);
        float xv = xs[((size_t)(b * N + t)) * F + lane];
        a1 += e1 * xv; s1 += e1;
        a2 += e2 * xv; s2 += e2;
    }
    size_t row = (size_t)c * NC;
    tot1[row + lane] = a1;
    tot2[row + lane] = a2;
    if (lane == 0) { tot1[row + 64] = s1; tot2[row + 64] = s2; }
}

// ---------------------------------------------------------------------------
// K4: in-place exclusive scans over NCH=1024 chunks. Wave per (arr,b,comp):
// 520 jobs = 130 blocks x 4 waves; 16 elems/lane + shfl_up wave scan.
// arr0 (tot1): exclusive SUFFIX; arr1 (tot2): exclusive PREFIX.
// ---------------------------------------------------------------------------
__global__ __launch_bounds__(256) void scan_kernel(
        float* __restrict__ tot1, float* __restrict__ tot2) {
    int wave = threadIdx.x >> 6, lane = threadIdx.x & 63;
    int job = blockIdx.x * 4 + wave;           // 0..519
    int arr = job >= (BZ * NC);
    int rem = job - arr * (BZ * NC);
    int b = rem / NC, comp = rem % NC;
    float* base = (arr ? tot2 : tot1) + ((size_t)b * NCH) * NC + comp;

    float v[16];
#pragma unroll
    for (int t = 0; t < 16; ++t) {
        int e = lane * 16 + t;
        int c = arr ? e : (NCH - 1 - e);       // suffix scan = reversed prefix
        v[t] = base[(size_t)c * NC];
    }
    float s = 0.f;
#pragma unroll
    for (int t = 0; t < 16; ++t) s += v[t];
    float inc = s;
#pragma unroll
    for (int off = 1; off < 64; off <<= 1) {
        float o = __shfl_up(inc, off, 64);
        if (lane >= off) inc += o;
    }
    float run = inc - s;                       // exclusive across lanes
#pragma unroll
    for (int t = 0; t < 16; ++t) {
        int e = lane * 16 + t;
        int c = arr ? e : (NCH - 1 - e);
        float vv = v[t];
        base[(size_t)c * NC] = run;
        run += vv;
    }
}

// ---------------------------------------------------------------------------
// K5: epilogue. grid BZ*64 x 1024 (16 waves, 4 rows each).
// p = p_arr[i]; c = min(p>>2, NCH-1); r0 = p - 4c; 4 CONTIGUOUS xs rows
// (no dependent id load). LDS transpose -> coalesced out[b][f][i].
// ---------------------------------------------------------------------------
__global__ __launch_bounds__(1024) void out_kernel(
        const float* __restrict__ karr, const float* __restrict__ q_sorted,
        const int* __restrict__ p_arr, const float* __restrict__ tot1,
        const float* __restrict__ tot2, const float* __restrict__ xs,
        float* __restrict__ out) {
    __shared__ float tile[64 * 65];
    int b = blockIdx.x >> 6;
    int i0 = (blockIdx.x & 63) * 64;
    int wave = threadIdx.x >> 6, lane = threadIdx.x & 63;
    const float* qsb = q_sorted + b * N;
    float Qmax = qsb[N - 1];

#pragma unroll
    for (int s = 0; s < 4; ++s) {
        int il = wave * 4 + s;
        int i = i0 + il;
        float kk = karr[b * N + i];
        int p = p_arr[b * N + i];
        int c = p >> 2; if (c > NCH - 1) c = NCH - 1;
        int r0 = p - (c << 2);
        float u = kk + Qmax;
        float M = fmaxf(u, 0.2f * u);
        float c1 = __expf(u - M);
        float c2 = __expf(0.2f * u - M);
        size_t row = ((size_t)(b * NCH + c)) * NC;
        float a1 = tot1[row + lane], s1 = tot1[row + 64];
        float a2 = tot2[row + lane], s2 = tot2[row + 64];
        int tb = c << 2;
#pragma unroll
        for (int r = 0; r < RPC; ++r) {
            float d = qsb[tb + r] - Qmax;
            float xv = xs[((size_t)(b * N + tb + r)) * F + lane];
            if (r >= r0) { float e1 = __expf(d);        a1 += e1 * xv; s1 += e1; }
            else         { float e2 = __expf(0.2f * d); a2 += e2 * xv; s2 += e2; }
        }
        float num = c1 * a1 + c2 * a2;
        float den = c1 * s1 + c2 * s2;
        tile[lane * 65 + il] = num / den;
    }
    __syncthreads();
#pragma unroll
    for (int rep = 0; rep < 4; ++rep) {
        int ff = rep * 16 + wave;
        out[((size_t)(b * F + ff)) * N + i0 + lane] = tile[ff * 65 + lane];
    }
}

// ---------------------------------------------------------------------------
extern "C" void kernel_launch(void* const* d_in, const int* in_sizes, int n_in,
                              void* d_out, int out_size, void* d_ws, size_t ws_size,
                              hipStream_t stream) {
    const float* x  = (const float*)d_in[0];
    const float* wk = (const float*)d_in[1];
    const float* wq = (const float*)d_in[2];
    float* out = (float*)d_out;

    // ws layout (floats): karr[BZ*N] | qkey(u64)[BZ*N] (=2*BZ*N floats) |
    //   q_sorted[BZ*N] | p_arr[BZ*N] | tot1[BZ*NCH*NC] | tot2[...] | xs[BZ*N*F]
    float* ws = (float*)d_ws;
    float* karr = ws;
    unsigned long long* qkey = (unsigned long long*)(ws + BZ * N);
    float* q_sorted = ws + 3 * BZ * N;
    int*   p_arr    = (int*)(ws + 4 * BZ * N);
    float* tot1     = ws + 5 * BZ * N;
    float* tot2     = tot1 + BZ * NCH * NC;
    float* xs       = tot2 + BZ * NCH * NC;

    kq_kernel<<<BZ * N / 4, 256, 0, stream>>>(x, wk, wq, karr, qkey);
    rank_kernel<<<BZ * 64, 1024, 0, stream>>>(x, karr, qkey, q_sorted, p_arr, xs);
    chunk_kernel<<<BZ * NCH / 4, 256, 0, stream>>>(xs, q_sorted, tot1, tot2);
    scan_kernel<<<130, 256, 0, stream>>>(tot1, tot2);
    out_kernel<<<BZ * 64, 1024, 0, stream>>>(karr, q_sorted, p_arr, tot1, tot2,
                                             xs, out);
}

// Round 6
// 92.722 us; speedup vs baseline: 2.4862x; 1.0960x over previous
//
#include <hip/hip_runtime.h>

#define N 4096
#define F 64
#define BZ 4
#define NC 65            // 64 features + 1 denominator component
// hierarchy: 64 superchunks x 16 subchunks x 4 rows = 4096 sorted rows

// order-preserving float <-> uint32 mapping
__device__ __forceinline__ unsigned int f2ord(float f) {
    unsigned int u = __float_as_uint(f);
    return (u & 0x80000000u) ? ~u : (u ^ 0x80000000u);
}
__device__ __forceinline__ float ord2f(unsigned int v) {
    unsigned int b = (v & 0x80000000u) ? (v ^ 0x80000000u) : ~v;
    return __uint_as_float(b);
}

// ---------------------------------------------------------------------------
// K1: karr[b][i] = x·wk (float); qkey[b][i] = (ord(x·wq)<<32)|i. Wave per row.
// ---------------------------------------------------------------------------
__global__ __launch_bounds__(256) void kq_kernel(
        const float* __restrict__ x, const float* __restrict__ wk,
        const float* __restrict__ wq, float* __restrict__ karr,
        unsigned long long* __restrict__ qkey) {
    int wave = blockIdx.x * 4 + (threadIdx.x >> 6);
    int lane = threadIdx.x & 63;
    int row = wave;                     // 0..BZ*N-1
    float xv = x[(size_t)row * F + lane];
    float kk = xv * wk[lane];
    float qq = xv * wq[lane];
    for (int off = 32; off > 0; off >>= 1) {
        kk += __shfl_down(kk, off, 64);
        qq += __shfl_down(qq, off, 64);
    }
    if (lane == 0) {
        karr[row] = kk;
        qkey[row] = ((unsigned long long)f2ord(qq) << 32)
                  | (unsigned int)(row & (N - 1));
    }
}

// ---------------------------------------------------------------------------
// K2: counting rank-sort on u64 keys + split points + x permutation.
// grid BZ*64 x 1024. Wave-uniform (broadcast) LDS reads; u64 compares.
//   rank_j = #{s : key_s < key_j}        (strict total order, exact)
//   p_j    = #{s : ord(q_s) < ord(-k_j)} (tie direction irrelevant: e^0 both)
// ---------------------------------------------------------------------------
__global__ __launch_bounds__(1024) void rank_kernel(
        const float* __restrict__ x, const float* __restrict__ karr,
        const unsigned long long* __restrict__ qkey,
        float* __restrict__ q_sorted, int* __restrict__ p_arr,
        float* __restrict__ xs) {
    __shared__ __align__(16) unsigned long long qs[N];   // 32 KB
    __shared__ unsigned short pc[16][64];
    __shared__ unsigned short pc2[16][64];
    __shared__ unsigned short rs[64];
    int b = blockIdx.x >> 6;
    int tid = threadIdx.x;
    int wave = tid >> 6, lane = tid & 63;
    const unsigned long long* qb = qkey + b * N;
    for (int t = tid; t < N; t += 1024) qs[t] = qb[t];
    __syncthreads();

    int jbase = (blockIdx.x & 63) * 64;
    int j = jbase + lane;
    unsigned long long myKey = qs[j];
    unsigned int thOu = f2ord(-karr[b * N + j]);
    int cnt = 0, cnt2 = 0;
    const ulonglong2* q2 = (const ulonglong2*)qs;
    int s0 = wave * 128;                      // ulonglong2 units
#pragma unroll 8
    for (int t2 = 0; t2 < 128; ++t2) {
        ulonglong2 v = q2[s0 + t2];
        cnt  += (int)(v.x < myKey) + (int)(v.y < myKey);
        cnt2 += (int)((unsigned int)(v.x >> 32) < thOu)
              + (int)((unsigned int)(v.y >> 32) < thOu);
    }
    pc[wave][lane] = (unsigned short)cnt;
    pc2[wave][lane] = (unsigned short)cnt2;
    __syncthreads();

    if (wave == 0) {
        int r = 0, p = 0;
#pragma unroll
        for (int pp = 0; pp < 16; ++pp) { r += pc[pp][lane]; p += pc2[pp][lane]; }
        q_sorted[b * N + r] = ord2f((unsigned int)(myKey >> 32));
        p_arr[b * N + j] = p;
        rs[lane] = (unsigned short)r;
    }
    __syncthreads();

    // permute x into sorted order: 4 rows per wave, coalesced 256B each
#pragma unroll
    for (int s = 0; s < 4; ++s) {
        int jl = wave * 4 + s;
        int r = rs[jl];
        xs[((size_t)(b * N + r)) * F + lane] =
            x[((size_t)(b * N + jbase + jl)) * F + lane];
    }
}

// ---------------------------------------------------------------------------
// K3: fused chunk totals + intra-superchunk scans.
// grid BZ*64 (block = superchunk of 64 sorted rows) x 1024 (wave = subchunk).
// Writes: sub1 = excl SUFFIX over subchunks within super (of e^{d} sums)
//         sub2 = excl PREFIX over subchunks within super (of e^{0.2d} sums)
//         sup1/sup2 = full superchunk totals (scanned later by out_kernel).
// ---------------------------------------------------------------------------
__global__ __launch_bounds__(1024) void chunkscan_kernel(
        const float* __restrict__ xs, const float* __restrict__ q_sorted,
        float* __restrict__ sub1, float* __restrict__ sub2,
        float* __restrict__ sup1, float* __restrict__ sup2) {
    __shared__ float l1[16][66], l2[16][66];
    int b = blockIdx.x >> 6;
    int sp = blockIdx.x & 63;
    int w = threadIdx.x >> 6, lane = threadIdx.x & 63;
    const float* qsb = q_sorted + b * N;
    float Qmax = qsb[N - 1];
    int base = sp * 64 + w * 4;               // sorted-row base of this sub
    float a1 = 0.f, a2 = 0.f, s1 = 0.f, s2 = 0.f;
#pragma unroll
    for (int r = 0; r < 4; ++r) {
        int t = base + r;
        float d = qsb[t] - Qmax;
        float e1 = __expf(d);
        float e2 = __expf(0.2f * d);
        float xv = xs[((size_t)(b * N + t)) * F + lane];
        a1 += e1 * xv; s1 += e1;
        a2 += e2 * xv; s2 += e2;
    }
    l1[w][lane] = a1; l2[w][lane] = a2;
    if (lane == 0) { l1[w][64] = s1; l2[w][64] = s2; }
    __syncthreads();

    float suf = 0.f, sufd = 0.f;
    for (int u = w + 1; u < 16; ++u) { suf += l1[u][lane]; sufd += l1[u][64]; }
    float pre = 0.f, pred = 0.f;
    for (int u = 0; u < w; ++u) { pre += l2[u][lane]; pred += l2[u][64]; }

    size_t srow = ((size_t)((b * 64 + sp) * 16 + w)) * NC;
    sub1[srow + lane] = suf;
    sub2[srow + lane] = pre;
    if (lane == 0) { sub1[srow + 64] = sufd; sub2[srow + 64] = pred; }

    size_t prow = ((size_t)(b * 64 + sp)) * NC;
    if (w == 0) {                              // suf over u>0 + own = total
        sup1[prow + lane] = suf + a1;
        if (lane == 0) sup1[prow + 64] = sufd + s1;
    }
    if (w == 15) {                             // pre over u<15 + own = total
        sup2[prow + lane] = pre + a2;
        if (lane == 0) sup2[prow + 64] = pred + s2;
    }
}

// ---------------------------------------------------------------------------
// K4: epilogue. grid BZ*64 x 1024 (16 waves x 4 rows).
// Loads 64 super-totals (2x65 comps), scans them in LDS (excl suffix for
// arr1, excl prefix for arr2), then per row i:
//   p; c=min(p>>2,1023); sp=c>>4; su=c&15; r0=p-4c
//   a = superscan[sp] + subscan[sp][su] + tail(4 xs rows, split at r0)
// LDS transpose -> coalesced out[b][f][i].
// ---------------------------------------------------------------------------
__global__ __launch_bounds__(1024) void out_kernel(
        const float* __restrict__ karr, const float* __restrict__ q_sorted,
        const int* __restrict__ p_arr, const float* __restrict__ sub1,
        const float* __restrict__ sub2, const float* __restrict__ sup1,
        const float* __restrict__ sup2, const float* __restrict__ xs,
        float* __restrict__ out) {
    __shared__ float sS1[64][66], sS2[64][66];   // 33.8 KB
    __shared__ float tile[64 * 65];              // 16.6 KB
    int b = blockIdx.x >> 6;
    int i0 = (blockIdx.x & 63) * 64;
    int tid = threadIdx.x;
    int wave = tid >> 6, lane = tid & 63;
    const float* qsb = q_sorted + b * N;
    float Qmax = qsb[N - 1];

    // load super totals (64 rows x 65 comps x 2 arrays)
    for (int s = wave; s < 64; s += 16) {
        size_t prow = ((size_t)(b * 64 + s)) * NC;
        sS1[s][lane] = sup1[prow + lane];
        sS2[s][lane] = sup2[prow + lane];
        if (lane == 0) { sS1[s][64] = sup1[prow + 64]; sS2[s][64] = sup2[prow + 64]; }
    }
    __syncthreads();
    // scan super totals: threads 0..64 -> arr1 comps (excl suffix),
    //                    threads 65..129 -> arr2 comps (excl prefix)
    if (tid < 65) {
        int comp = tid;
        float run = 0.f;
        for (int s = 63; s >= 0; --s) {
            float v = sS1[s][comp]; sS1[s][comp] = run; run += v;
        }
    } else if (tid < 130) {
        int comp = tid - 65;
        float run = 0.f;
        for (int s = 0; s < 64; ++s) {
            float v = sS2[s][comp]; sS2[s][comp] = run; run += v;
        }
    }
    __syncthreads();

#pragma unroll
    for (int s = 0; s < 4; ++s) {
        int il = wave * 4 + s;
        int i = i0 + il;
        float kk = karr[b * N + i];
        int p = p_arr[b * N + i];
        int c = p >> 2; if (c > 1023) c = 1023;
        int sp = c >> 4, su = c & 15;
        int r0 = p - (c << 2);
        float u = kk + Qmax;
        float M = fmaxf(u, 0.2f * u);
        float c1 = __expf(u - M);
        float c2 = __expf(0.2f * u - M);
        size_t srow = ((size_t)((b * 64 + sp) * 16 + su)) * NC;
        float a1 = sS1[sp][lane] + sub1[srow + lane];
        float s1 = sS1[sp][64] + sub1[srow + 64];
        float a2 = sS2[sp][lane] + sub2[srow + lane];
        float s2 = sS2[sp][64] + sub2[srow + 64];
        int tb = c << 2;
#pragma unroll
        for (int r = 0; r < 4; ++r) {
            float d = qsb[tb + r] - Qmax;
            float xv = xs[((size_t)(b * N + tb + r)) * F + lane];
            if (r >= r0) { float e1 = __expf(d);        a1 += e1 * xv; s1 += e1; }
            else         { float e2 = __expf(0.2f * d); a2 += e2 * xv; s2 += e2; }
        }
        float num = c1 * a1 + c2 * a2;
        float den = c1 * s1 + c2 * s2;
        tile[lane * 65 + il] = num / den;
    }
    __syncthreads();
#pragma unroll
    for (int rep = 0; rep < 4; ++rep) {
        int ff = rep * 16 + wave;
        out[((size_t)(b * F + ff)) * N + i0 + lane] = tile[ff * 65 + lane];
    }
}

// ---------------------------------------------------------------------------
extern "C" void kernel_launch(void* const* d_in, const int* in_sizes, int n_in,
                              void* d_out, int out_size, void* d_ws, size_t ws_size,
                              hipStream_t stream) {
    const float* x  = (const float*)d_in[0];
    const float* wk = (const float*)d_in[1];
    const float* wq = (const float*)d_in[2];
    float* out = (float*)d_out;

    // ws layout (floats): karr[BZ*N] | qkey(u64)[BZ*N] (=2*BZ*N floats) |
    //   q_sorted[BZ*N] | p_arr[BZ*N] | sub1[BZ*1024*NC] | sub2[...] |
    //   sup1[BZ*64*NC] | sup2[...] | xs[BZ*N*F]
    float* ws = (float*)d_ws;
    float* karr = ws;
    unsigned long long* qkey = (unsigned long long*)(ws + BZ * N);
    float* q_sorted = ws + 3 * BZ * N;
    int*   p_arr    = (int*)(ws + 4 * BZ * N);
    float* sub1     = ws + 5 * BZ * N;
    float* sub2     = sub1 + (size_t)BZ * 1024 * NC;
    float* sup1     = sub2 + (size_t)BZ * 1024 * NC;
    float* sup2     = sup1 + (size_t)BZ * 64 * NC;
    float* xs       = sup2 + (size_t)BZ * 64 * NC;

    kq_kernel<<<BZ * N / 4, 256, 0, stream>>>(x, wk, wq, karr, qkey);
    rank_kernel<<<BZ * 64, 1024, 0, stream>>>(x, karr, qkey, q_sorted, p_arr, xs);
    chunkscan_kernel<<<BZ * 64, 1024, 0, stream>>>(xs, q_sorted, sub1, sub2,
                                                   sup1, sup2);
    out_kernel<<<BZ * 64, 1024, 0, stream>>>(karr, q_sorted, p_arr, sub1, sub2,
                                             sup1, sup2, xs, out);
}